// Round 1
// baseline (852.561 us; speedup 1.0000x reference)
//
#include <hip/hip_runtime.h>
#include <hip/hip_bf16.h>
#include <cstdint>
#include <cstddef>

#define D 128

static inline size_t align256(size_t x){ return (x + 255) & ~(size_t)255; }

// ---------------------------------------------------------------------------
// Detect whether edge_index is stored as int64 or int32.
// If int64 (values < 2^31), every odd dword among the first 2E dwords is 0.
// If int32, odd dwords are random node ids in [0, 50000) -> almost surely nonzero.
// Reading first 2E dwords is safe for both layouts.
__global__ void detect_kernel(const int* __restrict__ ei, long long n32, int* __restrict__ flag){
  __shared__ int s;
  if (threadIdx.x == 0) s = 0;
  __syncthreads();
  int nz = 0;
  for (long long i = 2LL*threadIdx.x + 1; i < 4096 && i < n32; i += 512)
    nz |= (ei[i] != 0);
  if (nz) s = 1;              // benign race, all writers write 1
  __syncthreads();
  if (threadIdx.x == 0) *flag = (s ? 0 : 1);   // 1 => int64
}

__device__ __forceinline__ void load_edge(const void* ei, int E, int is64, int e, int& s, int& d){
  if (is64) {
    const long long* p = (const long long*)ei;
    s = (int)p[e]; d = (int)p[(size_t)E + e];
  } else {
    const int* p = (const int*)ei;
    s = p[e]; d = p[(size_t)E + e];
  }
}

// ---------------------------------------------------------------------------
// deg histogram over dst (real edges only; self-loop added analytically later)
__global__ void hist_kernel(const void* __restrict__ ei, int E, const int* __restrict__ flag,
                            int* __restrict__ deg){
  int e = blockIdx.x * blockDim.x + threadIdx.x;
  if (e >= E) return;
  int is64 = *flag;
  int s, d;
  load_edge(ei, E, is64, e, s, d);
  atomicAdd(&deg[d], 1);
}

// dis[v] = rsqrt(deg[v] + 1)   (+1 = self loop; always >= 1)
__global__ void dis_kernel(const int* __restrict__ deg, float* __restrict__ dis, int N){
  int v = blockIdx.x * blockDim.x + threadIdx.x;
  if (v >= N) return;
  dis[v] = rsqrtf((float)(deg[v] + 1));
}

// ---------- exclusive scan of deg -> rowptr (3 small kernels) ----------
// scan_partial: each block scans 1024 elements (256 thr x 4), writes local
// exclusive prefixes to rowptr and the block total to blockSums.
__global__ void scan_partial(const int* __restrict__ deg, int* __restrict__ rowptr,
                             int* __restrict__ blockSums, int N){
  __shared__ int sd[256];
  int t = threadIdx.x;
  int base = blockIdx.x * 1024 + t * 4;
  int v[4]; int s = 0;
  #pragma unroll
  for (int j = 0; j < 4; ++j){ v[j] = (base + j < N) ? deg[base + j] : 0; s += v[j]; }
  sd[t] = s; __syncthreads();
  for (int off = 1; off < 256; off <<= 1){
    int x = (t >= off) ? sd[t - off] : 0;
    __syncthreads();
    sd[t] += x;
    __syncthreads();
  }
  int run = sd[t] - s;          // exclusive prefix of this thread within block
  #pragma unroll
  for (int j = 0; j < 4; ++j){
    if (base + j < N) rowptr[base + j] = run;
    run += v[j];
  }
  if (t == 255) blockSums[blockIdx.x] = sd[255];
}

// scan_blocksums: single block scans up to 256 block sums (N<=262144 ok)
__global__ void scan_blocksums(int* __restrict__ blockSums, int nblk,
                               int* __restrict__ rowptr, int N, int E){
  __shared__ int sd[256];
  int t = threadIdx.x;
  int v = (t < nblk) ? blockSums[t] : 0;
  sd[t] = v; __syncthreads();
  for (int off = 1; off < 256; off <<= 1){
    int x = (t >= off) ? sd[t - off] : 0;
    __syncthreads();
    sd[t] += x;
    __syncthreads();
  }
  if (t < nblk) blockSums[t] = sd[t] - v;   // exclusive
  if (t == 0) rowptr[N] = E;                // total = sum(deg) = E exactly
}

__global__ void scan_add(int* __restrict__ rowptr, const int* __restrict__ blockSums, int N){
  int i = blockIdx.x * blockDim.x + threadIdx.x;
  if (i >= N) return;
  rowptr[i] += blockSums[i >> 10];
}

// ---------------------------------------------------------------------------
// scatter edges into CSR (grouped by dst); csr_w pre-multiplies dis[src]
__global__ void fill_kernel(const void* __restrict__ ei, int E, const int* __restrict__ flag,
                            const int* __restrict__ rowptr, int* __restrict__ cursor,
                            const float* __restrict__ dis,
                            int* __restrict__ csr_src, float* __restrict__ csr_w){
  int e = blockIdx.x * blockDim.x + threadIdx.x;
  if (e >= E) return;
  int is64 = *flag;
  int s, d;
  load_edge(ei, E, is64, e, s, d);
  int pos = atomicAdd(&cursor[d], 1);
  int idx = rowptr[d] + pos;
  csr_src[idx] = s;
  csr_w[idx] = dis[s];
}

// ---------------------------------------------------------------------------
// out[v] = dis[v] * ( sum_{u->v} in[u]*dis[u]  +  in[v]*dis[v] )
// one node per 128-thread half-block; channel c per thread; coalesced row reads
__global__ __launch_bounds__(256) void agg_kernel(
    const float* __restrict__ in, float* __restrict__ out,
    const int* __restrict__ rowptr, const int* __restrict__ csr_src,
    const float* __restrict__ csr_w, const float* __restrict__ dis, int N){
  int v = blockIdx.x * 2 + (threadIdx.x >> 7);
  if (v >= N) return;
  int c = threadIdx.x & 127;
  float dv = dis[v];
  int beg = rowptr[v], end = rowptr[v + 1];
  float acc = in[(size_t)v * D + c] * dv;   // self loop
  int e = beg;
  for (; e + 1 < end; e += 2){
    int u0 = csr_src[e],     u1 = csr_src[e + 1];
    float w0 = csr_w[e],     w1 = csr_w[e + 1];
    float x0 = in[(size_t)u0 * D + c];
    float x1 = in[(size_t)u1 * D + c];
    acc += x0 * w0;
    acc += x1 * w1;
  }
  if (e < end){
    int u0 = csr_src[e];
    acc += in[(size_t)u0 * D + c] * csr_w[e];
  }
  out[(size_t)v * D + c] = acc * dv;
}

// ---------------------------------------------------------------------------
// f32 GEMM  out[N,128] = A[N,128] @ W[128,128]  + epilogue
// EPI 0: out = relu(AW + bias)
// EPI 1: out = (A@W + bias) + eps * exp(A@W2 + bias2) * 0.1   (VAE reparam)
#define BM 64
#define BN 64
#define BK 16
#define BMP 68   // padded LDS leading dim (17*16B rows: aligned float4, 2-way banks = free)

template<int EPI>
__global__ __launch_bounds__(256) void gemm128(
    const float* __restrict__ A, const float* __restrict__ W, const float* __restrict__ bias,
    const float* __restrict__ W2, const float* __restrict__ bias2,
    const float* __restrict__ eps, float* __restrict__ out, int N){

  __shared__ __align__(16) float As[BK][BMP];
  __shared__ __align__(16) float Bs[BK][BN];
  __shared__ __align__(16) float Bs2[BK][BN];

  int t  = threadIdx.x;
  int tx = t & 15;          // col group (4 cols)
  int ty = t >> 4;          // row group (4 rows)
  int rowBase = blockIdx.x * BM;
  int colBase = blockIdx.y * BN;

  // A-tile load mapping: 64 rows x 16 k, float4 per thread
  int arow = t >> 2;
  int ak   = (t & 3) * 4;
  // W-tile load mapping: 16 k x 64 n, float4 per thread
  int wk = t >> 4;
  int wn = (t & 15) * 4;

  float acc[4][4] = {};
  float acc2[4][4] = {};

  for (int k0 = 0; k0 < 128; k0 += BK){
    float4 a4 = {0.f, 0.f, 0.f, 0.f};
    int r = rowBase + arow;
    if (r < N) a4 = *(const float4*)&A[(size_t)r * D + k0 + ak];
    As[ak + 0][arow] = a4.x;
    As[ak + 1][arow] = a4.y;
    As[ak + 2][arow] = a4.z;
    As[ak + 3][arow] = a4.w;
    *(float4*)&Bs[wk][wn] = *(const float4*)&W[(size_t)(k0 + wk) * D + colBase + wn];
    if (EPI == 1)
      *(float4*)&Bs2[wk][wn] = *(const float4*)&W2[(size_t)(k0 + wk) * D + colBase + wn];
    __syncthreads();

    #pragma unroll
    for (int k = 0; k < BK; ++k){
      float4 ra = *(const float4*)&As[k][ty * 4];
      float4 rb = *(const float4*)&Bs[k][tx * 4];
      float a_[4] = {ra.x, ra.y, ra.z, ra.w};
      float b_[4] = {rb.x, rb.y, rb.z, rb.w};
      #pragma unroll
      for (int i = 0; i < 4; ++i)
        #pragma unroll
        for (int j = 0; j < 4; ++j)
          acc[i][j] = fmaf(a_[i], b_[j], acc[i][j]);
      if (EPI == 1){
        float4 rb2 = *(const float4*)&Bs2[k][tx * 4];
        float b2_[4] = {rb2.x, rb2.y, rb2.z, rb2.w};
        #pragma unroll
        for (int i = 0; i < 4; ++i)
          #pragma unroll
          for (int j = 0; j < 4; ++j)
            acc2[i][j] = fmaf(a_[i], b2_[j], acc2[i][j]);
      }
    }
    __syncthreads();
  }

  int n0 = colBase + tx * 4;
  float4 bi = *(const float4*)&bias[n0];
  float bias4[4] = {bi.x, bi.y, bi.z, bi.w};
  float bias24[4] = {0.f, 0.f, 0.f, 0.f};
  if (EPI == 1){
    float4 bi2 = *(const float4*)&bias2[n0];
    bias24[0] = bi2.x; bias24[1] = bi2.y; bias24[2] = bi2.z; bias24[3] = bi2.w;
  }

  #pragma unroll
  for (int i = 0; i < 4; ++i){
    int r = rowBase + ty * 4 + i;
    if (r >= N) continue;
    float4 o;
    if (EPI == 0){
      o.x = fmaxf(acc[i][0] + bias4[0], 0.f);
      o.y = fmaxf(acc[i][1] + bias4[1], 0.f);
      o.z = fmaxf(acc[i][2] + bias4[2], 0.f);
      o.w = fmaxf(acc[i][3] + bias4[3], 0.f);
    } else {
      float4 e4 = *(const float4*)&eps[(size_t)r * D + n0];
      float ev[4] = {e4.x, e4.y, e4.z, e4.w};
      float zo[4];
      #pragma unroll
      for (int j = 0; j < 4; ++j){
        float mu = acc[i][j] + bias4[j];
        float ls = acc2[i][j] + bias24[j];
        zo[j] = mu + ev[j] * __expf(ls) * 0.1f;
      }
      o.x = zo[0]; o.y = zo[1]; o.z = zo[2]; o.w = zo[3];
    }
    *(float4*)&out[(size_t)r * D + n0] = o;
  }
}

// ---------------------------------------------------------------------------
extern "C" void kernel_launch(void* const* d_in, const int* in_sizes, int n_in,
                              void* d_out, int out_size, void* d_ws, size_t ws_size,
                              hipStream_t stream){
  const float* x   = (const float*)d_in[0];
  const void*  ei  = d_in[1];
  const float* eps = (const float*)d_in[2];
  const float* W1  = (const float*)d_in[3];  const float* b1  = (const float*)d_in[4];
  const float* W2  = (const float*)d_in[5];  const float* b2  = (const float*)d_in[6];
  const float* Wmu = (const float*)d_in[7];  const float* bmu = (const float*)d_in[8];
  const float* Wls = (const float*)d_in[9];  const float* bls = (const float*)d_in[10];
  const float* W5  = (const float*)d_in[11]; const float* b5  = (const float*)d_in[12];
  const float* W6  = (const float*)d_in[13]; const float* b6  = (const float*)d_in[14];

  const int N = in_sizes[0] / D;
  const int E = in_sizes[1] / 2;
  float* out = (float*)d_out;

  // workspace layout (~33 MB; d_out doubles as the GEMM-output ping buffer)
  char* ws = (char*)d_ws;
  size_t off = 0;
  auto alloc = [&](size_t bytes){ char* p = ws + off; off += align256(bytes); return p; };
  int*   flag      = (int*)  alloc(256);
  int*   deg       = (int*)  alloc((size_t)N * 4);
  int*   rowptr    = (int*)  alloc(((size_t)N + 1) * 4);
  int*   cursor    = (int*)  alloc((size_t)N * 4);
  float* dis       = (float*)alloc((size_t)N * 4);
  int*   blockSums = (int*)  alloc(1024);
  int*   csr_src   = (int*)  alloc((size_t)E * 4);
  float* csr_w     = (float*)alloc((size_t)E * 4);
  float* buf0      = (float*)alloc((size_t)N * D * 4);
  (void)ws_size; (void)n_in; (void)out_size;

  hipMemsetAsync(deg, 0, (size_t)N * 4, stream);
  hipMemsetAsync(cursor, 0, (size_t)N * 4, stream);

  detect_kernel<<<1, 256, 0, stream>>>((const int*)ei, (long long)2 * E, flag);
  hist_kernel<<<(E + 255) / 256, 256, 0, stream>>>(ei, E, flag, deg);
  dis_kernel<<<(N + 255) / 256, 256, 0, stream>>>(deg, dis, N);

  int nblk = (N + 1023) / 1024;   // 49 for N=50000 (<=256 supported)
  scan_partial<<<nblk, 256, 0, stream>>>(deg, rowptr, blockSums, N);
  scan_blocksums<<<1, 256, 0, stream>>>(blockSums, nblk, rowptr, N, E);
  scan_add<<<(N + 255) / 256, 256, 0, stream>>>(rowptr, blockSums, N);

  fill_kernel<<<(E + 255) / 256, 256, 0, stream>>>(ei, E, flag, rowptr, cursor, dis, csr_src, csr_w);

  dim3 gg((N + BM - 1) / BM, 128 / BN);
  int aggGrid = (N + 1) / 2;

  // layer 1: relu((Â x) W1 + b1)
  agg_kernel<<<aggGrid, 256, 0, stream>>>(x, buf0, rowptr, csr_src, csr_w, dis, N);
  gemm128<0><<<gg, 256, 0, stream>>>(buf0, W1, b1, nullptr, nullptr, nullptr, out, N);
  // layer 2
  agg_kernel<<<aggGrid, 256, 0, stream>>>(out, buf0, rowptr, csr_src, csr_w, dis, N);
  gemm128<0><<<gg, 256, 0, stream>>>(buf0, W2, b2, nullptr, nullptr, nullptr, out, N);
  // mu / logstd share one aggregation; fused reparametrization
  agg_kernel<<<aggGrid, 256, 0, stream>>>(out, buf0, rowptr, csr_src, csr_w, dis, N);
  gemm128<1><<<gg, 256, 0, stream>>>(buf0, Wmu, bmu, Wls, bls, eps, out, N);
  // layer 5
  agg_kernel<<<aggGrid, 256, 0, stream>>>(out, buf0, rowptr, csr_src, csr_w, dis, N);
  gemm128<0><<<gg, 256, 0, stream>>>(buf0, W5, b5, nullptr, nullptr, nullptr, out, N);
  // layer 6
  agg_kernel<<<aggGrid, 256, 0, stream>>>(out, buf0, rowptr, csr_src, csr_w, dis, N);
  gemm128<0><<<gg, 256, 0, stream>>>(buf0, W6, b6, nullptr, nullptr, nullptr, out, N);
}

// Round 2
// 596.033 us; speedup vs baseline: 1.4304x; 1.4304x over previous
//
#include <hip/hip_runtime.h>
#include <hip/hip_bf16.h>
#include <cstdint>
#include <cstddef>

#define D 128

typedef _Float16 f16;
typedef f16 f16x2 __attribute__((ext_vector_type(2)));
typedef f16 f16x4 __attribute__((ext_vector_type(4)));
typedef f16 f16x8 __attribute__((ext_vector_type(8)));
typedef float f32x4 __attribute__((ext_vector_type(4)));

static inline size_t align256(size_t x){ return (x + 255) & ~(size_t)255; }

// ---------------------------------------------------------------------------
// int64 vs int32 edge_index detection (odd dwords of int64 data are all 0)
__global__ void detect_kernel(const int* __restrict__ ei, long long n32, int* __restrict__ flag){
  __shared__ int s;
  if (threadIdx.x == 0) s = 0;
  __syncthreads();
  int nz = 0;
  for (long long i = 2LL*threadIdx.x + 1; i < 4096 && i < n32; i += 512)
    nz |= (ei[i] != 0);
  if (nz) s = 1;
  __syncthreads();
  if (threadIdx.x == 0) *flag = (s ? 0 : 1);   // 1 => int64
}

__device__ __forceinline__ void load_edge(const void* ei, int E, int is64, int e, int& s, int& d){
  if (is64) {
    const long long* p = (const long long*)ei;
    s = (int)p[e]; d = (int)p[(size_t)E + e];
  } else {
    const int* p = (const int*)ei;
    s = p[e]; d = p[(size_t)E + e];
  }
}

// ---------------------------------------------------------------------------
__global__ void hist_kernel(const void* __restrict__ ei, int E, const int* __restrict__ flag,
                            int* __restrict__ deg){
  int e = blockIdx.x * blockDim.x + threadIdx.x;
  if (e >= E) return;
  int is64 = *flag;
  int s, d;
  load_edge(ei, E, is64, e, s, d);
  atomicAdd(&deg[d], 1);
}

__global__ void dis_kernel(const int* __restrict__ deg, float* __restrict__ dis, int N){
  int v = blockIdx.x * blockDim.x + threadIdx.x;
  if (v >= N) return;
  dis[v] = rsqrtf((float)(deg[v] + 1));
}

// ---------- exclusive scan of deg -> rowptr ----------
__global__ void scan_partial(const int* __restrict__ deg, int* __restrict__ rowptr,
                             int* __restrict__ blockSums, int N){
  __shared__ int sd[256];
  int t = threadIdx.x;
  int base = blockIdx.x * 1024 + t * 4;
  int v[4]; int s = 0;
  #pragma unroll
  for (int j = 0; j < 4; ++j){ v[j] = (base + j < N) ? deg[base + j] : 0; s += v[j]; }
  sd[t] = s; __syncthreads();
  for (int off = 1; off < 256; off <<= 1){
    int x = (t >= off) ? sd[t - off] : 0;
    __syncthreads();
    sd[t] += x;
    __syncthreads();
  }
  int run = sd[t] - s;
  #pragma unroll
  for (int j = 0; j < 4; ++j){
    if (base + j < N) rowptr[base + j] = run;
    run += v[j];
  }
  if (t == 255) blockSums[blockIdx.x] = sd[255];
}

__global__ void scan_blocksums(int* __restrict__ blockSums, int nblk,
                               int* __restrict__ rowptr, int N, int E){
  __shared__ int sd[256];
  int t = threadIdx.x;
  int v = (t < nblk) ? blockSums[t] : 0;
  sd[t] = v; __syncthreads();
  for (int off = 1; off < 256; off <<= 1){
    int x = (t >= off) ? sd[t - off] : 0;
    __syncthreads();
    sd[t] += x;
    __syncthreads();
  }
  if (t < nblk) blockSums[t] = sd[t] - v;
  if (t == 0) rowptr[N] = E;
}

__global__ void scan_add(int* __restrict__ rowptr, const int* __restrict__ blockSums, int N){
  int i = blockIdx.x * blockDim.x + threadIdx.x;
  if (i >= N) return;
  rowptr[i] += blockSums[i >> 10];
}

// ---------------------------------------------------------------------------
__global__ void fill_kernel(const void* __restrict__ ei, int E, const int* __restrict__ flag,
                            const int* __restrict__ rowptr, int* __restrict__ cursor,
                            const float* __restrict__ dis,
                            int* __restrict__ csr_src, float* __restrict__ csr_w){
  int e = blockIdx.x * blockDim.x + threadIdx.x;
  if (e >= E) return;
  int is64 = *flag;
  int s, d;
  load_edge(ei, E, is64, e, s, d);
  int pos = atomicAdd(&cursor[d], 1);
  int idx = rowptr[d] + pos;
  csr_src[idx] = s;
  csr_w[idx] = dis[s];
}

// ---------------------------------------------------------------------------
// cast f32 -> fp16 (4 elems per thread)
__global__ void cast_f32_f16(const float* __restrict__ in, f16* __restrict__ out, int n4){
  int i = blockIdx.x * blockDim.x + threadIdx.x;
  if (i >= n4) return;
  float4 v = ((const float4*)in)[i];
  f16x4 o; o[0]=(f16)v.x; o[1]=(f16)v.y; o[2]=(f16)v.z; o[3]=(f16)v.w;
  ((f16x4*)out)[i] = o;
}

// transpose+cast 6 weight matrices: Wt[w][n][k] = W_w[k][n], fp16
__global__ void prep_w(const float* __restrict__ Wa, const float* __restrict__ Wb,
                       const float* __restrict__ Wc, const float* __restrict__ Wd,
                       const float* __restrict__ We, const float* __restrict__ Wf,
                       f16* __restrict__ Wt){
  int i = blockIdx.x * 256 + threadIdx.x;   // 6*16384 total
  int w = i >> 14, rem = i & 16383;
  int n = rem >> 7, k = rem & 127;
  const float* Wp = (w==0)?Wa:(w==1)?Wb:(w==2)?Wc:(w==3)?Wd:(w==4)?We:Wf;
  Wt[i] = (f16)Wp[k*128 + n];
}

// ---------------------------------------------------------------------------
// fp16 aggregation: out[v] = dis[v]*( sum_{u->v} in[u]*dis[u] + in[v]*dis[v] )
// one wave per node; lane handles channels 2c,2c+1 (4B loads, 256B/row/wave)
__global__ __launch_bounds__(256) void agg16(
    const f16* __restrict__ in, f16* __restrict__ out,
    const int* __restrict__ rowptr, const int* __restrict__ csr_src,
    const float* __restrict__ csr_w, const float* __restrict__ dis, int N){
  int v = blockIdx.x * 4 + (threadIdx.x >> 6);
  if (v >= N) return;
  int c2 = (threadIdx.x & 63) * 2;
  float dv = dis[v];
  int beg = rowptr[v], end = rowptr[v + 1];
  f16x2 sv = *(const f16x2*)&in[(size_t)v * D + c2];
  float acc0 = (float)sv[0] * dv, acc1 = (float)sv[1] * dv;
  int e = beg;
  for (; e + 1 < end; e += 2){
    int u0 = csr_src[e],  u1 = csr_src[e + 1];
    float w0 = csr_w[e],  w1 = csr_w[e + 1];
    f16x2 h0 = *(const f16x2*)&in[(size_t)u0 * D + c2];
    f16x2 h1 = *(const f16x2*)&in[(size_t)u1 * D + c2];
    acc0 += (float)h0[0] * w0; acc1 += (float)h0[1] * w0;
    acc0 += (float)h1[0] * w1; acc1 += (float)h1[1] * w1;
  }
  if (e < end){
    int u = csr_src[e]; float w = csr_w[e];
    f16x2 h = *(const f16x2*)&in[(size_t)u * D + c2];
    acc0 += (float)h[0] * w; acc1 += (float)h[1] * w;
  }
  f16x2 o; o[0] = (f16)(acc0 * dv); o[1] = (f16)(acc1 * dv);
  *(f16x2*)&out[(size_t)v * D + c2] = o;
}

// ---------------------------------------------------------------------------
// MFMA GEMM: out[N,128] = A[N,128](fp16) @ W[128,128] + epilogue
//   EPI 0: fp16 out = relu(AW + b)
//   EPI 1: fp16 out = (A Wmu + bmu) + eps * exp(A Wls + bls) * 0.1
//   EPI 2: f32  out = relu(AW + b)      (final layer -> d_out)
// W staged in LDS as Wt[n][k] fp16 with 16B-quad XOR swizzle (2-way banks).
// Block = 256 thr = 4 waves; block tile 64 rows x 128 cols; wave tile 16x128.
// A frag (16x16x32_f16): lane l holds A[r0+(l&15)][s*32+(l>>4)*8 + 0..7]
// C/D: col = l&15, row = r0+(l>>4)*4+i   [m89-verified layout]
template<int EPI>
__global__ __launch_bounds__(256) void gemm_mfma(
    const f16* __restrict__ A, const f16* __restrict__ Wt, const float* __restrict__ bias,
    const f16* __restrict__ Wt2, const float* __restrict__ bias2,
    const float* __restrict__ eps, f16* __restrict__ out16, float* __restrict__ outf, int N){

  extern __shared__ __align__(16) f16 Ws[];   // [128][128] (+ second matrix for EPI1)

  int t = threadIdx.x;
  // ---- stage W (quad-swizzled): row r, half p; quad j stored at j^(r&7)
  {
    int r = t & 127, p = t >> 7;
    const float4* src = (const float4*)&Wt[r * 128 + p * 64];
    f16* dstrow = &Ws[r * 128];
    #pragma unroll
    for (int i = 0; i < 8; ++i){
      int q = p * 8 + i;
      *(float4*)&dstrow[(q ^ (r & 7)) * 8] = src[i];
    }
    if (EPI == 1){
      const float4* src2 = (const float4*)&Wt2[r * 128 + p * 64];
      f16* dstrow2 = &Ws[16384 + r * 128];
      #pragma unroll
      for (int i = 0; i < 8; ++i){
        int q = p * 8 + i;
        *(float4*)&dstrow2[(q ^ (r & 7)) * 8] = src2[i];
      }
    }
  }
  __syncthreads();

  int wave = t >> 6, lane = t & 63;
  int r0 = blockIdx.x * 64 + wave * 16;
  int lrow = lane & 15, hi = lane >> 4;

  // ---- A fragments (4 K-steps), clamped row for tail tile
  int rr = min(r0 + lrow, N - 1);
  const f16* arow = &A[(size_t)rr * D + hi * 8];
  f16x8 a[4];
  #pragma unroll
  for (int s = 0; s < 4; ++s) a[s] = *(const f16x8*)&arow[s * 32];

  f32x4 acc[8] = {};
  f32x4 acc2[8] = {};

  #pragma unroll
  for (int s = 0; s < 4; ++s){
    #pragma unroll
    for (int tt = 0; tt < 8; ++tt){
      int n = tt * 16 + lrow;
      int q = (s * 4 + hi) ^ (lrow & 7);
      f16x8 b = *(const f16x8*)&Ws[n * 128 + q * 8];
      acc[tt] = __builtin_amdgcn_mfma_f32_16x16x32_f16(a[s], b, acc[tt], 0, 0, 0);
      if (EPI == 1){
        f16x8 b2 = *(const f16x8*)&Ws[16384 + n * 128 + q * 8];
        acc2[tt] = __builtin_amdgcn_mfma_f32_16x16x32_f16(a[s], b2, acc2[tt], 0, 0, 0);
      }
    }
  }

  // ---- epilogue
  int orow0 = r0 + hi * 4;
  #pragma unroll
  for (int tt = 0; tt < 8; ++tt){
    int col = tt * 16 + lrow;
    float bv = bias[col];
    float bv2 = (EPI == 1) ? bias2[col] : 0.f;
    #pragma unroll
    for (int i = 0; i < 4; ++i){
      int r = orow0 + i;
      if (r >= N) continue;
      float v = acc[tt][i] + bv;
      if (EPI == 0){
        out16[(size_t)r * D + col] = (f16)fmaxf(v, 0.f);
      } else if (EPI == 1){
        float ls = acc2[tt][i] + bv2;
        float z = v + eps[(size_t)r * D + col] * __expf(ls) * 0.1f;
        out16[(size_t)r * D + col] = (f16)z;
      } else {
        outf[(size_t)r * D + col] = fmaxf(v, 0.f);
      }
    }
  }
}

// ---------------------------------------------------------------------------
extern "C" void kernel_launch(void* const* d_in, const int* in_sizes, int n_in,
                              void* d_out, int out_size, void* d_ws, size_t ws_size,
                              hipStream_t stream){
  const float* x   = (const float*)d_in[0];
  const void*  ei  = d_in[1];
  const float* eps = (const float*)d_in[2];
  const float* W1  = (const float*)d_in[3];  const float* b1  = (const float*)d_in[4];
  const float* W2  = (const float*)d_in[5];  const float* b2  = (const float*)d_in[6];
  const float* Wmu = (const float*)d_in[7];  const float* bmu = (const float*)d_in[8];
  const float* Wls = (const float*)d_in[9];  const float* bls = (const float*)d_in[10];
  const float* W5  = (const float*)d_in[11]; const float* b5  = (const float*)d_in[12];
  const float* W6  = (const float*)d_in[13]; const float* b6  = (const float*)d_in[14];

  const int N = in_sizes[0] / D;
  const int E = in_sizes[1] / 2;
  float* out = (float*)d_out;

  char* ws = (char*)d_ws;
  size_t off = 0;
  auto alloc = [&](size_t bytes){ char* p = ws + off; off += align256(bytes); return p; };
  int*   flag      = (int*)  alloc(256);
  int*   deg       = (int*)  alloc((size_t)N * 4);
  int*   rowptr    = (int*)  alloc(((size_t)N + 1) * 4);
  int*   cursor    = (int*)  alloc((size_t)N * 4);
  float* dis       = (float*)alloc((size_t)N * 4);
  int*   blockSums = (int*)  alloc(1024);
  int*   csr_src   = (int*)  alloc((size_t)E * 4);
  float* csr_w     = (float*)alloc((size_t)E * 4);
  f16*   Wt        = (f16*)  alloc((size_t)6 * 128 * 128 * 2);
  f16*   bufA      = (f16*)  alloc((size_t)N * D * 2);
  f16*   bufB      = (f16*)  alloc((size_t)N * D * 2);
  (void)ws_size; (void)n_in; (void)out_size;

  hipMemsetAsync(deg, 0, (size_t)N * 4, stream);
  hipMemsetAsync(cursor, 0, (size_t)N * 4, stream);

  detect_kernel<<<1, 256, 0, stream>>>((const int*)ei, (long long)2 * E, flag);
  hist_kernel<<<(E + 255) / 256, 256, 0, stream>>>(ei, E, flag, deg);
  dis_kernel<<<(N + 255) / 256, 256, 0, stream>>>(deg, dis, N);

  int nblk = (N + 1023) / 1024;
  scan_partial<<<nblk, 256, 0, stream>>>(deg, rowptr, blockSums, N);
  scan_blocksums<<<1, 256, 0, stream>>>(blockSums, nblk, rowptr, N, E);
  scan_add<<<(N + 255) / 256, 256, 0, stream>>>(rowptr, blockSums, N);

  fill_kernel<<<(E + 255) / 256, 256, 0, stream>>>(ei, E, flag, rowptr, cursor, dis, csr_src, csr_w);

  cast_f32_f16<<<(N * D / 4 + 255) / 256, 256, 0, stream>>>(x, bufB, N * D / 4);
  prep_w<<<(6 * 16384) / 256, 256, 0, stream>>>(W1, W2, Wmu, Wls, W5, W6, Wt);

  int aggGrid = (N + 3) / 4;
  int gemmGrid = (N + 63) / 64;
  size_t lds1 = 128 * 128 * sizeof(f16);       // 32 KB
  size_t lds2 = 2 * 128 * 128 * sizeof(f16);   // 64 KB (EPI1)

  // layer 1
  agg16<<<aggGrid, 256, 0, stream>>>(bufB, bufA, rowptr, csr_src, csr_w, dis, N);
  gemm_mfma<0><<<gemmGrid, 256, lds1, stream>>>(bufA, Wt + 0*16384, b1, nullptr, nullptr, nullptr, bufB, nullptr, N);
  // layer 2
  agg16<<<aggGrid, 256, 0, stream>>>(bufB, bufA, rowptr, csr_src, csr_w, dis, N);
  gemm_mfma<0><<<gemmGrid, 256, lds1, stream>>>(bufA, Wt + 1*16384, b2, nullptr, nullptr, nullptr, bufB, nullptr, N);
  // mu/logstd share aggregation; fused reparametrization
  agg16<<<aggGrid, 256, 0, stream>>>(bufB, bufA, rowptr, csr_src, csr_w, dis, N);
  gemm_mfma<1><<<gemmGrid, 256, lds2, stream>>>(bufA, Wt + 2*16384, bmu, Wt + 3*16384, bls, eps, bufB, nullptr, N);
  // layer 5
  agg16<<<aggGrid, 256, 0, stream>>>(bufB, bufA, rowptr, csr_src, csr_w, dis, N);
  gemm_mfma<0><<<gemmGrid, 256, lds1, stream>>>(bufA, Wt + 4*16384, b5, nullptr, nullptr, nullptr, bufB, nullptr, N);
  // layer 6 -> f32 d_out
  agg16<<<aggGrid, 256, 0, stream>>>(bufB, bufA, rowptr, csr_src, csr_w, dis, N);
  gemm_mfma<2><<<gemmGrid, 256, lds1, stream>>>(bufA, Wt + 5*16384, b6, nullptr, nullptr, nullptr, nullptr, out, N);
}

// Round 3
// 515.126 us; speedup vs baseline: 1.6551x; 1.1571x over previous
//
#include <hip/hip_runtime.h>
#include <hip/hip_bf16.h>
#include <cstdint>
#include <cstddef>

#define D 128

typedef _Float16 f16;
typedef f16 f16x2 __attribute__((ext_vector_type(2)));
typedef f16 f16x4 __attribute__((ext_vector_type(4)));
typedef f16 f16x8 __attribute__((ext_vector_type(8)));
typedef float f32x4 __attribute__((ext_vector_type(4)));

static inline size_t align256(size_t x){ return (x + 255) & ~(size_t)255; }

// ---------------------------------------------------------------------------
// int64 vs int32 edge_index detection (odd dwords of int64 data are all 0)
__global__ void detect_kernel(const int* __restrict__ ei, long long n32, int* __restrict__ flag){
  __shared__ int s;
  if (threadIdx.x == 0) s = 0;
  __syncthreads();
  int nz = 0;
  for (long long i = 2LL*threadIdx.x + 1; i < 4096 && i < n32; i += 512)
    nz |= (ei[i] != 0);
  if (nz) s = 1;
  __syncthreads();
  if (threadIdx.x == 0) *flag = (s ? 0 : 1);   // 1 => int64
}

__device__ __forceinline__ void load_edge(const void* ei, int E, int is64, int e, int& s, int& d){
  if (is64) {
    const long long* p = (const long long*)ei;
    s = (int)p[e]; d = (int)p[(size_t)E + e];
  } else {
    const int* p = (const int*)ei;
    s = p[e]; d = p[(size_t)E + e];
  }
}

// ---------------------------------------------------------------------------
__global__ void hist_kernel(const void* __restrict__ ei, int E, const int* __restrict__ flag,
                            int* __restrict__ deg){
  int e = blockIdx.x * blockDim.x + threadIdx.x;
  if (e >= E) return;
  int is64 = *flag;
  int s, d;
  load_edge(ei, E, is64, e, s, d);
  atomicAdd(&deg[d], 1);
}

// ---------- exclusive scan of deg -> rowptr (dis fused in) ----------
__global__ void scan_partial(const int* __restrict__ deg, int* __restrict__ rowptr,
                             int* __restrict__ blockSums, float* __restrict__ dis, int N){
  __shared__ int sd[256];
  int t = threadIdx.x;
  int base = blockIdx.x * 1024 + t * 4;
  int v[4]; int s = 0;
  #pragma unroll
  for (int j = 0; j < 4; ++j){ v[j] = (base + j < N) ? deg[base + j] : 0; s += v[j]; }
  #pragma unroll
  for (int j = 0; j < 4; ++j)
    if (base + j < N) dis[base + j] = rsqrtf((float)(v[j] + 1));
  sd[t] = s; __syncthreads();
  for (int off = 1; off < 256; off <<= 1){
    int x = (t >= off) ? sd[t - off] : 0;
    __syncthreads();
    sd[t] += x;
    __syncthreads();
  }
  int run = sd[t] - s;
  #pragma unroll
  for (int j = 0; j < 4; ++j){
    if (base + j < N) rowptr[base + j] = run;
    run += v[j];
  }
  if (t == 255) blockSums[blockIdx.x] = sd[255];
}

__global__ void scan_blocksums(int* __restrict__ blockSums, int nblk,
                               int* __restrict__ rowptr, int N, int E){
  __shared__ int sd[256];
  int t = threadIdx.x;
  int v = (t < nblk) ? blockSums[t] : 0;
  sd[t] = v; __syncthreads();
  for (int off = 1; off < 256; off <<= 1){
    int x = (t >= off) ? sd[t - off] : 0;
    __syncthreads();
    sd[t] += x;
    __syncthreads();
  }
  if (t < nblk) blockSums[t] = sd[t] - v;
  if (t == 0) rowptr[N] = E;
}

__global__ void scan_add(int* __restrict__ rowptr, const int* __restrict__ blockSums, int N){
  int i = blockIdx.x * blockDim.x + threadIdx.x;
  if (i >= N) return;
  rowptr[i] += blockSums[i >> 10];
}

// ---------------------------------------------------------------------------
// scatter edges into CSR (src only; dis[src] is folded into activations)
__global__ void fill_kernel(const void* __restrict__ ei, int E, const int* __restrict__ flag,
                            const int* __restrict__ rowptr, int* __restrict__ cursor,
                            int* __restrict__ csr_src){
  int e = blockIdx.x * blockDim.x + threadIdx.x;
  if (e >= E) return;
  int is64 = *flag;
  int s, d;
  load_edge(ei, E, is64, e, s, d);
  int pos = atomicAdd(&cursor[d], 1);
  csr_src[rowptr[d] + pos] = s;
}

// ---------------------------------------------------------------------------
// cast + pre-scale: out[v][c] = f16(in[v][c] * dis[v])
__global__ void cast_scale(const float* __restrict__ in, const float* __restrict__ dis,
                           f16* __restrict__ out, int n4){
  int i = blockIdx.x * blockDim.x + threadIdx.x;
  if (i >= n4) return;
  float dv = dis[i >> 5];                 // 32 float4-groups per row of 128
  float4 v = ((const float4*)in)[i];
  f16x4 o; o[0]=(f16)(v.x*dv); o[1]=(f16)(v.y*dv); o[2]=(f16)(v.z*dv); o[3]=(f16)(v.w*dv);
  ((f16x4*)out)[i] = o;
}

// transpose+cast 6 weight matrices: Wt[w][n][k] = W_w[k][n], fp16
__global__ void prep_w(const float* __restrict__ Wa, const float* __restrict__ Wb,
                       const float* __restrict__ Wc, const float* __restrict__ Wd,
                       const float* __restrict__ We, const float* __restrict__ Wf,
                       f16* __restrict__ Wt){
  int i = blockIdx.x * 256 + threadIdx.x;   // 6*16384 total
  int w = i >> 14, rem = i & 16383;
  int n = rem >> 7, k = rem & 127;
  const float* Wp = (w==0)?Wa:(w==1)?Wb:(w==2)?Wc:(w==3)?Wd:(w==4)?We:Wf;
  Wt[i] = (f16)Wp[k*128 + n];
}

// ---------------------------------------------------------------------------
// unweighted fp16 aggregation over pre-scaled activations:
//   out[v] = f16( dis[v] * ( sum_{u->v} in[u] + in[v] ) )
// one wave per node; lane covers channels 2c,2c+1; 4 gathers in flight
__global__ __launch_bounds__(256) void agg16(
    const f16* __restrict__ in, f16* __restrict__ out,
    const int* __restrict__ rowptr, const int* __restrict__ csr_src,
    const float* __restrict__ dis, int N){
  int v = blockIdx.x * 4 + (threadIdx.x >> 6);
  if (v >= N) return;
  int c2 = (threadIdx.x & 63) * 2;
  float dv = dis[v];
  int beg = rowptr[v], end = rowptr[v + 1];
  f16x2 sv = *(const f16x2*)&in[(size_t)v * D + c2];
  float acc0 = (float)sv[0], acc1 = (float)sv[1];
  int e = beg;
  for (; e + 3 < end; e += 4){
    int u0 = csr_src[e],     u1 = csr_src[e + 1];
    int u2 = csr_src[e + 2], u3 = csr_src[e + 3];
    f16x2 h0 = *(const f16x2*)&in[(size_t)u0 * D + c2];
    f16x2 h1 = *(const f16x2*)&in[(size_t)u1 * D + c2];
    f16x2 h2 = *(const f16x2*)&in[(size_t)u2 * D + c2];
    f16x2 h3 = *(const f16x2*)&in[(size_t)u3 * D + c2];
    acc0 += (float)h0[0] + (float)h1[0] + (float)h2[0] + (float)h3[0];
    acc1 += (float)h0[1] + (float)h1[1] + (float)h2[1] + (float)h3[1];
  }
  for (; e < end; ++e){
    int u = csr_src[e];
    f16x2 h = *(const f16x2*)&in[(size_t)u * D + c2];
    acc0 += (float)h[0]; acc1 += (float)h[1];
  }
  f16x2 o; o[0] = (f16)(acc0 * dv); o[1] = (f16)(acc1 * dv);
  *(f16x2*)&out[(size_t)v * D + c2] = o;
}

// ---------------------------------------------------------------------------
// MFMA GEMM: out = A[N,128](fp16) @ W[128,128] + epilogue (output pre-scaled
// by dis[row] for the next aggregation, except the final f32 layer).
//   EPI 0: fp16 out = relu(AW + b) * dis[r]
//   EPI 1: fp16 out = ((A Wmu + bmu) + eps * exp(A Wls + bls) * 0.1) * dis[r]
//   EPI 2: f32  out = relu(AW + b)            (final layer -> d_out)
// W staged in LDS as Wt[n][k] fp16, 16B-quad XOR swizzle (2-way banks = free).
// Block = 4 waves; tile 64 rows x 128 cols; wave tile 16x128.
// A frag (16x16x32_f16): lane l holds A[r0+(l&15)][s*32+(l>>4)*8 + 0..7]
// C/D: col = l&15, row = r0+(l>>4)*4+i   [m89-verified layout]
template<int EPI>
__global__ __launch_bounds__(256) void gemm_mfma(
    const f16* __restrict__ A, const f16* __restrict__ Wt, const float* __restrict__ bias,
    const f16* __restrict__ Wt2, const float* __restrict__ bias2,
    const float* __restrict__ eps, const float* __restrict__ dis,
    f16* __restrict__ out16, float* __restrict__ outf, int N){

  extern __shared__ __align__(16) f16 Ws[];   // [128][128] (+ second matrix for EPI1)

  int t = threadIdx.x;
  {
    int r = t & 127, p = t >> 7;
    const float4* src = (const float4*)&Wt[r * 128 + p * 64];
    f16* dstrow = &Ws[r * 128];
    #pragma unroll
    for (int i = 0; i < 8; ++i){
      int q = p * 8 + i;
      *(float4*)&dstrow[(q ^ (r & 7)) * 8] = src[i];
    }
    if (EPI == 1){
      const float4* src2 = (const float4*)&Wt2[r * 128 + p * 64];
      f16* dstrow2 = &Ws[16384 + r * 128];
      #pragma unroll
      for (int i = 0; i < 8; ++i){
        int q = p * 8 + i;
        *(float4*)&dstrow2[(q ^ (r & 7)) * 8] = src2[i];
      }
    }
  }
  __syncthreads();

  int wave = t >> 6, lane = t & 63;
  int r0 = blockIdx.x * 64 + wave * 16;
  int lrow = lane & 15, hi = lane >> 4;

  int rr = min(r0 + lrow, N - 1);
  const f16* arow = &A[(size_t)rr * D + hi * 8];
  f16x8 a[4];
  #pragma unroll
  for (int s = 0; s < 4; ++s) a[s] = *(const f16x8*)&arow[s * 32];

  f32x4 acc[8] = {};
  f32x4 acc2[8] = {};

  #pragma unroll
  for (int s = 0; s < 4; ++s){
    #pragma unroll
    for (int tt = 0; tt < 8; ++tt){
      int n = tt * 16 + lrow;
      int q = (s * 4 + hi) ^ (lrow & 7);
      f16x8 b = *(const f16x8*)&Ws[n * 128 + q * 8];
      acc[tt] = __builtin_amdgcn_mfma_f32_16x16x32_f16(a[s], b, acc[tt], 0, 0, 0);
      if (EPI == 1){
        f16x8 b2 = *(const f16x8*)&Ws[16384 + n * 128 + q * 8];
        acc2[tt] = __builtin_amdgcn_mfma_f32_16x16x32_f16(a[s], b2, acc2[tt], 0, 0, 0);
      }
    }
  }

  int orow0 = r0 + hi * 4;
  #pragma unroll
  for (int tt = 0; tt < 8; ++tt){
    int col = tt * 16 + lrow;
    float bv = bias[col];
    float bv2 = (EPI == 1) ? bias2[col] : 0.f;
    #pragma unroll
    for (int i = 0; i < 4; ++i){
      int r = orow0 + i;
      if (r >= N) continue;
      float v = acc[tt][i] + bv;
      if (EPI == 0){
        out16[(size_t)r * D + col] = (f16)(fmaxf(v, 0.f) * dis[r]);
      } else if (EPI == 1){
        float ls = acc2[tt][i] + bv2;
        float z = v + eps[(size_t)r * D + col] * __expf(ls) * 0.1f;
        out16[(size_t)r * D + col] = (f16)(z * dis[r]);
      } else {
        outf[(size_t)r * D + col] = fmaxf(v, 0.f);
      }
    }
  }
}

// ---------------------------------------------------------------------------
extern "C" void kernel_launch(void* const* d_in, const int* in_sizes, int n_in,
                              void* d_out, int out_size, void* d_ws, size_t ws_size,
                              hipStream_t stream){
  const float* x   = (const float*)d_in[0];
  const void*  ei  = d_in[1];
  const float* eps = (const float*)d_in[2];
  const float* W1  = (const float*)d_in[3];  const float* b1  = (const float*)d_in[4];
  const float* W2  = (const float*)d_in[5];  const float* b2  = (const float*)d_in[6];
  const float* Wmu = (const float*)d_in[7];  const float* bmu = (const float*)d_in[8];
  const float* Wls = (const float*)d_in[9];  const float* bls = (const float*)d_in[10];
  const float* W5  = (const float*)d_in[11]; const float* b5  = (const float*)d_in[12];
  const float* W6  = (const float*)d_in[13]; const float* b6  = (const float*)d_in[14];

  const int N = in_sizes[0] / D;
  const int E = in_sizes[1] / 2;
  float* out = (float*)d_out;

  char* ws = (char*)d_ws;
  size_t off = 0;
  auto alloc = [&](size_t bytes){ char* p = ws + off; off += align256(bytes); return p; };
  int*   flag      = (int*)  alloc(256);
  int*   deg       = (int*)  alloc((size_t)N * 4);
  int*   rowptr    = (int*)  alloc(((size_t)N + 1) * 4);
  int*   cursor    = (int*)  alloc((size_t)N * 4);
  float* dis       = (float*)alloc((size_t)N * 4);
  int*   blockSums = (int*)  alloc(1024);
  int*   csr_src   = (int*)  alloc((size_t)E * 4);
  f16*   Wt        = (f16*)  alloc((size_t)6 * 128 * 128 * 2);
  f16*   bufA      = (f16*)  alloc((size_t)N * D * 2);
  f16*   bufB      = (f16*)  alloc((size_t)N * D * 2);
  (void)ws_size; (void)n_in; (void)out_size;

  hipMemsetAsync(deg, 0, (size_t)N * 4, stream);
  hipMemsetAsync(cursor, 0, (size_t)N * 4, stream);

  detect_kernel<<<1, 256, 0, stream>>>((const int*)ei, (long long)2 * E, flag);
  hist_kernel<<<(E + 255) / 256, 256, 0, stream>>>(ei, E, flag, deg);

  int nblk = (N + 1023) / 1024;
  scan_partial<<<nblk, 256, 0, stream>>>(deg, rowptr, blockSums, dis, N);
  scan_blocksums<<<1, 256, 0, stream>>>(blockSums, nblk, rowptr, N, E);
  scan_add<<<(N + 255) / 256, 256, 0, stream>>>(rowptr, blockSums, N);

  fill_kernel<<<(E + 255) / 256, 256, 0, stream>>>(ei, E, flag, rowptr, cursor, csr_src);

  cast_scale<<<(N * D / 4 + 255) / 256, 256, 0, stream>>>(x, dis, bufB, N * D / 4);
  prep_w<<<(6 * 16384) / 256, 256, 0, stream>>>(W1, W2, Wmu, Wls, W5, W6, Wt);

  int aggGrid = (N + 3) / 4;
  int gemmGrid = (N + 63) / 64;
  size_t lds1 = 128 * 128 * sizeof(f16);       // 32 KB
  size_t lds2 = 2 * 128 * 128 * sizeof(f16);   // 64 KB (EPI1)

  // layer 1
  agg16<<<aggGrid, 256, 0, stream>>>(bufB, bufA, rowptr, csr_src, dis, N);
  gemm_mfma<0><<<gemmGrid, 256, lds1, stream>>>(bufA, Wt + 0*16384, b1, nullptr, nullptr, nullptr, dis, bufB, nullptr, N);
  // layer 2
  agg16<<<aggGrid, 256, 0, stream>>>(bufB, bufA, rowptr, csr_src, dis, N);
  gemm_mfma<0><<<gemmGrid, 256, lds1, stream>>>(bufA, Wt + 1*16384, b2, nullptr, nullptr, nullptr, dis, bufB, nullptr, N);
  // mu/logstd share aggregation; fused reparametrization
  agg16<<<aggGrid, 256, 0, stream>>>(bufB, bufA, rowptr, csr_src, dis, N);
  gemm_mfma<1><<<gemmGrid, 256, lds2, stream>>>(bufA, Wt + 2*16384, bmu, Wt + 3*16384, bls, eps, dis, bufB, nullptr, N);
  // layer 5
  agg16<<<aggGrid, 256, 0, stream>>>(bufB, bufA, rowptr, csr_src, dis, N);
  gemm_mfma<0><<<gemmGrid, 256, lds1, stream>>>(bufA, Wt + 4*16384, b5, nullptr, nullptr, nullptr, dis, bufB, nullptr, N);
  // layer 6 -> f32 d_out
  agg16<<<aggGrid, 256, 0, stream>>>(bufB, bufA, rowptr, csr_src, dis, N);
  gemm_mfma<2><<<gemmGrid, 256, lds1, stream>>>(bufA, Wt + 5*16384, b6, nullptr, nullptr, nullptr, dis, nullptr, out, N);
}

// Round 4
// 457.005 us; speedup vs baseline: 1.8655x; 1.1272x over previous
//
#include <hip/hip_runtime.h>
#include <hip/hip_bf16.h>
#include <cstdint>
#include <cstddef>

#define D 128
#define NWG 200        // workgroups for edge binning passes

typedef _Float16 f16;
typedef f16 f16x2 __attribute__((ext_vector_type(2)));
typedef f16 f16x4 __attribute__((ext_vector_type(4)));
typedef f16 f16x8 __attribute__((ext_vector_type(8)));
typedef float f32x4 __attribute__((ext_vector_type(4)));

static inline size_t align256(size_t x){ return (x + 255) & ~(size_t)255; }

// ---------------------------------------------------------------------------
// int64 vs int32 edge_index detection (odd dwords of int64 data are all 0)
__global__ void detect_kernel(const int* __restrict__ ei, long long n32, int* __restrict__ flag){
  __shared__ int s;
  if (threadIdx.x == 0) s = 0;
  __syncthreads();
  int nz = 0;
  for (long long i = 2LL*threadIdx.x + 1; i < 4096 && i < n32; i += 512)
    nz |= (ei[i] != 0);
  if (nz) s = 1;
  __syncthreads();
  if (threadIdx.x == 0) *flag = (s ? 0 : 1);   // 1 => int64
}

__device__ __forceinline__ void load_edge(const void* ei, int E, int is64, int e, int& s, int& d){
  if (is64) {
    const long long* p = (const long long*)ei;
    s = (int)p[e]; d = (int)p[(size_t)E + e];
  } else {
    const int* p = (const int*)ei;
    s = p[e]; d = p[(size_t)E + e];
  }
}

// ---------------------------------------------------------------------------
// Pass A: per-(bucket, wg) histogram via LDS counters. No global atomics.
// glob_hist layout: [b * NWG + wg]
__global__ __launch_bounds__(256) void passA_hist(
    const void* __restrict__ ei, int E, const int* __restrict__ flag,
    int* __restrict__ glob_hist, int NB){
  __shared__ int cnt[256];
  int t = threadIdx.x, wg = blockIdx.x;
  cnt[t] = 0;
  __syncthreads();
  int is64 = *flag;
  int chunk = (E + NWG - 1) / NWG;
  int lo = wg * chunk, hi = min(lo + chunk, E);
  for (int e = lo + t; e < hi; e += 256){
    int s, d;
    load_edge(ei, E, is64, e, s, d);
    atomicAdd(&cnt[d >> 8], 1);
  }
  __syncthreads();
  for (int b = t; b < NB; b += 256)
    glob_hist[b * NWG + wg] = cnt[b];
}

// ---------- generic exclusive scan (3 kernels), arr length L, arr[L]=total ----
__global__ void scan_partial(const int* __restrict__ src, int* __restrict__ dst,
                             int* __restrict__ blockSums, int L){
  __shared__ int sd[256];
  int t = threadIdx.x;
  int base = blockIdx.x * 1024 + t * 4;
  int v[4]; int s = 0;
  #pragma unroll
  for (int j = 0; j < 4; ++j){ v[j] = (base + j < L) ? src[base + j] : 0; s += v[j]; }
  sd[t] = s; __syncthreads();
  for (int off = 1; off < 256; off <<= 1){
    int x = (t >= off) ? sd[t - off] : 0;
    __syncthreads();
    sd[t] += x;
    __syncthreads();
  }
  int run = sd[t] - s;
  #pragma unroll
  for (int j = 0; j < 4; ++j){
    if (base + j < L) dst[base + j] = run;
    run += v[j];
  }
  if (t == 255) blockSums[blockIdx.x] = sd[255];
}

__global__ void scan_blocksums(int* __restrict__ blockSums, int nblk,
                               int* __restrict__ dst, int L, int total){
  __shared__ int sd[256];
  int t = threadIdx.x;
  int v = (t < nblk) ? blockSums[t] : 0;
  sd[t] = v; __syncthreads();
  for (int off = 1; off < 256; off <<= 1){
    int x = (t >= off) ? sd[t - off] : 0;
    __syncthreads();
    sd[t] += x;
    __syncthreads();
  }
  if (t < nblk) blockSums[t] = sd[t] - v;
  if (t == 0) dst[L] = total;
}

__global__ void scan_add(int* __restrict__ dst, const int* __restrict__ blockSums, int L){
  int i = blockIdx.x * blockDim.x + threadIdx.x;
  if (i >= L) return;
  dst[i] += blockSums[i >> 10];
}

// ---------------------------------------------------------------------------
// Pass B: scatter packed edges (src | dstLow<<16) into bucket-grouped array.
// Positions come from LDS cursors seeded with the scanned (bucket,wg) offsets,
// so every wg writes an exclusive region -> no cross-XCD line ping-pong.
__global__ __launch_bounds__(256) void passB_scatter(
    const void* __restrict__ ei, int E, const int* __restrict__ flag,
    const int* __restrict__ bucketOff, int NB, unsigned* __restrict__ packed){
  __shared__ int cur[256];
  int t = threadIdx.x, wg = blockIdx.x;
  for (int b = t; b < NB; b += 256)
    cur[b] = bucketOff[b * NWG + wg];
  __syncthreads();
  int is64 = *flag;
  int chunk = (E + NWG - 1) / NWG;
  int lo = wg * chunk, hi = min(lo + chunk, E);
  for (int e = lo + t; e < hi; e += 256){
    int s, d;
    load_edge(ei, E, is64, e, s, d);
    int pos = atomicAdd(&cur[d >> 8], 1);
    packed[pos] = (unsigned)s | ((unsigned)(d & 255) << 16);
  }
}

// ---------------------------------------------------------------------------
// Pass C: one wg per bucket (256 dst nodes). Local counts -> local scan ->
// rowptr + dis, then scatter csr_src within the wg-private region.
__global__ __launch_bounds__(256) void passC_csr(
    const unsigned* __restrict__ packed, const int* __restrict__ bucketOff,
    int NB, int N, int E,
    int* __restrict__ rowptr, float* __restrict__ dis, int* __restrict__ csr_src){
  __shared__ int degl[256];
  __shared__ int sd[256];
  __shared__ int cur[256];
  int t = threadIdx.x, b = blockIdx.x;
  int begin = bucketOff[(size_t)b * NWG];
  int endb  = bucketOff[(size_t)(b + 1) * NWG];
  degl[t] = 0;
  __syncthreads();
  for (int i = begin + t; i < endb; i += 256)
    atomicAdd(&degl[(packed[i] >> 16) & 255], 1);
  __syncthreads();
  int dv = degl[t];
  sd[t] = dv; __syncthreads();
  for (int off = 1; off < 256; off <<= 1){
    int x = (t >= off) ? sd[t - off] : 0;
    __syncthreads();
    sd[t] += x;
    __syncthreads();
  }
  int localOff = sd[t] - dv;     // exclusive prefix within bucket
  int v = b * 256 + t;
  if (v < N){
    rowptr[v] = begin + localOff;
    dis[v] = rsqrtf((float)(dv + 1));
  }
  if (b == NB - 1 && t == 0) rowptr[N] = E;
  cur[t] = begin + localOff;
  __syncthreads();
  for (int i = begin + t; i < endb; i += 256){
    unsigned p = packed[i];
    int pos = atomicAdd(&cur[(p >> 16) & 255], 1);
    csr_src[pos] = (int)(p & 0xFFFFu);
  }
}

// ---------------------------------------------------------------------------
// cast + pre-scale: out[v][c] = f16(in[v][c] * dis[v])
__global__ void cast_scale(const float* __restrict__ in, const float* __restrict__ dis,
                           f16* __restrict__ out, int n4){
  int i = blockIdx.x * blockDim.x + threadIdx.x;
  if (i >= n4) return;
  float dv = dis[i >> 5];                 // 32 float4-groups per row of 128
  float4 v = ((const float4*)in)[i];
  f16x4 o; o[0]=(f16)(v.x*dv); o[1]=(f16)(v.y*dv); o[2]=(f16)(v.z*dv); o[3]=(f16)(v.w*dv);
  ((f16x4*)out)[i] = o;
}

// transpose+cast 6 weight matrices: Wt[w][n][k] = W_w[k][n], fp16
__global__ void prep_w(const float* __restrict__ Wa, const float* __restrict__ Wb,
                       const float* __restrict__ Wc, const float* __restrict__ Wd,
                       const float* __restrict__ We, const float* __restrict__ Wf,
                       f16* __restrict__ Wt){
  int i = blockIdx.x * 256 + threadIdx.x;   // 6*16384 total
  int w = i >> 14, rem = i & 16383;
  int n = rem >> 7, k = rem & 127;
  const float* Wp = (w==0)?Wa:(w==1)?Wb:(w==2)?Wc:(w==3)?Wd:(w==4)?We:Wf;
  Wt[i] = (f16)Wp[k*128 + n];
}

// ---------------------------------------------------------------------------
// unweighted fp16 aggregation over pre-scaled activations:
//   out[v] = f16( dis[v] * ( sum_{u->v} in[u] + in[v] ) )
// one wave per node; lane covers channels 2c,2c+1; 4 gathers in flight
__global__ __launch_bounds__(256) void agg16(
    const f16* __restrict__ in, f16* __restrict__ out,
    const int* __restrict__ rowptr, const int* __restrict__ csr_src,
    const float* __restrict__ dis, int N){
  int v = blockIdx.x * 4 + (threadIdx.x >> 6);
  if (v >= N) return;
  int c2 = (threadIdx.x & 63) * 2;
  float dv = dis[v];
  int beg = rowptr[v], end = rowptr[v + 1];
  f16x2 sv = *(const f16x2*)&in[(size_t)v * D + c2];
  float acc0 = (float)sv[0], acc1 = (float)sv[1];
  int e = beg;
  for (; e + 3 < end; e += 4){
    int u0 = csr_src[e],     u1 = csr_src[e + 1];
    int u2 = csr_src[e + 2], u3 = csr_src[e + 3];
    f16x2 h0 = *(const f16x2*)&in[(size_t)u0 * D + c2];
    f16x2 h1 = *(const f16x2*)&in[(size_t)u1 * D + c2];
    f16x2 h2 = *(const f16x2*)&in[(size_t)u2 * D + c2];
    f16x2 h3 = *(const f16x2*)&in[(size_t)u3 * D + c2];
    acc0 += (float)h0[0] + (float)h1[0] + (float)h2[0] + (float)h3[0];
    acc1 += (float)h0[1] + (float)h1[1] + (float)h2[1] + (float)h3[1];
  }
  for (; e < end; ++e){
    int u = csr_src[e];
    f16x2 h = *(const f16x2*)&in[(size_t)u * D + c2];
    acc0 += (float)h[0]; acc1 += (float)h[1];
  }
  f16x2 o; o[0] = (f16)(acc0 * dv); o[1] = (f16)(acc1 * dv);
  *(f16x2*)&out[(size_t)v * D + c2] = o;
}

// ---------------------------------------------------------------------------
// MFMA GEMM: out = A[N,128](fp16) @ W[128,128] + epilogue (output pre-scaled
// by dis[row] for the next aggregation, except the final f32 layer).
//   EPI 0: fp16 out = relu(AW + b) * dis[r]
//   EPI 1: fp16 out = ((A Wmu + bmu) + eps * exp(A Wls + bls) * 0.1) * dis[r]
//   EPI 2: f32  out = relu(AW + b)            (final layer -> d_out)
template<int EPI>
__global__ __launch_bounds__(256) void gemm_mfma(
    const f16* __restrict__ A, const f16* __restrict__ Wt, const float* __restrict__ bias,
    const f16* __restrict__ Wt2, const float* __restrict__ bias2,
    const float* __restrict__ eps, const float* __restrict__ dis,
    f16* __restrict__ out16, float* __restrict__ outf, int N){

  extern __shared__ __align__(16) f16 Ws[];   // [128][128] (+ second matrix for EPI1)

  int t = threadIdx.x;
  {
    int r = t & 127, p = t >> 7;
    const float4* src = (const float4*)&Wt[r * 128 + p * 64];
    f16* dstrow = &Ws[r * 128];
    #pragma unroll
    for (int i = 0; i < 8; ++i){
      int q = p * 8 + i;
      *(float4*)&dstrow[(q ^ (r & 7)) * 8] = src[i];
    }
    if (EPI == 1){
      const float4* src2 = (const float4*)&Wt2[r * 128 + p * 64];
      f16* dstrow2 = &Ws[16384 + r * 128];
      #pragma unroll
      for (int i = 0; i < 8; ++i){
        int q = p * 8 + i;
        *(float4*)&dstrow2[(q ^ (r & 7)) * 8] = src2[i];
      }
    }
  }
  __syncthreads();

  int wave = t >> 6, lane = t & 63;
  int r0 = blockIdx.x * 64 + wave * 16;
  int lrow = lane & 15, hi = lane >> 4;

  int rr = min(r0 + lrow, N - 1);
  const f16* arow = &A[(size_t)rr * D + hi * 8];
  f16x8 a[4];
  #pragma unroll
  for (int s = 0; s < 4; ++s) a[s] = *(const f16x8*)&arow[s * 32];

  f32x4 acc[8] = {};
  f32x4 acc2[8] = {};

  #pragma unroll
  for (int s = 0; s < 4; ++s){
    #pragma unroll
    for (int tt = 0; tt < 8; ++tt){
      int n = tt * 16 + lrow;
      int q = (s * 4 + hi) ^ (lrow & 7);
      f16x8 b = *(const f16x8*)&Ws[n * 128 + q * 8];
      acc[tt] = __builtin_amdgcn_mfma_f32_16x16x32_f16(a[s], b, acc[tt], 0, 0, 0);
      if (EPI == 1){
        f16x8 b2 = *(const f16x8*)&Ws[16384 + n * 128 + q * 8];
        acc2[tt] = __builtin_amdgcn_mfma_f32_16x16x32_f16(a[s], b2, acc2[tt], 0, 0, 0);
      }
    }
  }

  int orow0 = r0 + hi * 4;
  #pragma unroll
  for (int tt = 0; tt < 8; ++tt){
    int col = tt * 16 + lrow;
    float bv = bias[col];
    float bv2 = (EPI == 1) ? bias2[col] : 0.f;
    #pragma unroll
    for (int i = 0; i < 4; ++i){
      int r = orow0 + i;
      if (r >= N) continue;
      float v = acc[tt][i] + bv;
      if (EPI == 0){
        out16[(size_t)r * D + col] = (f16)(fmaxf(v, 0.f) * dis[r]);
      } else if (EPI == 1){
        float ls = acc2[tt][i] + bv2;
        float z = v + eps[(size_t)r * D + col] * __expf(ls) * 0.1f;
        out16[(size_t)r * D + col] = (f16)(z * dis[r]);
      } else {
        outf[(size_t)r * D + col] = fmaxf(v, 0.f);
      }
    }
  }
}

// ---------------------------------------------------------------------------
extern "C" void kernel_launch(void* const* d_in, const int* in_sizes, int n_in,
                              void* d_out, int out_size, void* d_ws, size_t ws_size,
                              hipStream_t stream){
  const float* x   = (const float*)d_in[0];
  const void*  ei  = d_in[1];
  const float* eps = (const float*)d_in[2];
  const float* W1  = (const float*)d_in[3];  const float* b1  = (const float*)d_in[4];
  const float* W2  = (const float*)d_in[5];  const float* b2  = (const float*)d_in[6];
  const float* Wmu = (const float*)d_in[7];  const float* bmu = (const float*)d_in[8];
  const float* Wls = (const float*)d_in[9];  const float* bls = (const float*)d_in[10];
  const float* W5  = (const float*)d_in[11]; const float* b5  = (const float*)d_in[12];
  const float* W6  = (const float*)d_in[13]; const float* b6  = (const float*)d_in[14];

  const int N = in_sizes[0] / D;
  const int E = in_sizes[1] / 2;
  const int NB = (N + 255) >> 8;            // dst buckets of 256 nodes
  const int L  = NB * NWG;                  // (bucket, wg) table length
  float* out = (float*)d_out;

  char* ws = (char*)d_ws;
  size_t off = 0;
  auto alloc = [&](size_t bytes){ char* p = ws + off; off += align256(bytes); return p; };
  int*      flag      = (int*)     alloc(256);
  int*      glob_hist = (int*)     alloc(((size_t)L + 1) * 4);
  int*      bucketOff = (int*)     alloc(((size_t)L + 1) * 4);
  int*      blockSums = (int*)     alloc(1024);
  int*      rowptr    = (int*)     alloc(((size_t)N + 1) * 4);
  float*    dis       = (float*)   alloc((size_t)N * 4);
  unsigned* packed    = (unsigned*)alloc((size_t)E * 4);
  int*      csr_src   = (int*)     alloc((size_t)E * 4);
  f16*      Wt        = (f16*)     alloc((size_t)6 * 128 * 128 * 2);
  f16*      bufA      = (f16*)     alloc((size_t)N * D * 2);
  f16*      bufB      = (f16*)     alloc((size_t)N * D * 2);
  (void)ws_size; (void)n_in; (void)out_size;

  detect_kernel<<<1, 256, 0, stream>>>((const int*)ei, (long long)2 * E, flag);

  // CSR build: LDS-staged counting sort by dst bucket (no global atomics)
  passA_hist<<<NWG, 256, 0, stream>>>(ei, E, flag, glob_hist, NB);
  int nblk = (L + 1023) / 1024;
  scan_partial<<<nblk, 256, 0, stream>>>(glob_hist, bucketOff, blockSums, L);
  scan_blocksums<<<1, 256, 0, stream>>>(blockSums, nblk, bucketOff, L, E);
  scan_add<<<(L + 255) / 256, 256, 0, stream>>>(bucketOff, blockSums, L);
  passB_scatter<<<NWG, 256, 0, stream>>>(ei, E, flag, bucketOff, NB, packed);
  passC_csr<<<NB, 256, 0, stream>>>(packed, bucketOff, NB, N, E, rowptr, dis, csr_src);

  cast_scale<<<(N * D / 4 + 255) / 256, 256, 0, stream>>>(x, dis, bufB, N * D / 4);
  prep_w<<<(6 * 16384) / 256, 256, 0, stream>>>(W1, W2, Wmu, Wls, W5, W6, Wt);

  int aggGrid = (N + 3) / 4;
  int gemmGrid = (N + 63) / 64;
  size_t lds1 = 128 * 128 * sizeof(f16);       // 32 KB
  size_t lds2 = 2 * 128 * 128 * sizeof(f16);   // 64 KB (EPI1)

  // layer 1
  agg16<<<aggGrid, 256, 0, stream>>>(bufB, bufA, rowptr, csr_src, dis, N);
  gemm_mfma<0><<<gemmGrid, 256, lds1, stream>>>(bufA, Wt + 0*16384, b1, nullptr, nullptr, nullptr, dis, bufB, nullptr, N);
  // layer 2
  agg16<<<aggGrid, 256, 0, stream>>>(bufB, bufA, rowptr, csr_src, dis, N);
  gemm_mfma<0><<<gemmGrid, 256, lds1, stream>>>(bufA, Wt + 1*16384, b2, nullptr, nullptr, nullptr, dis, bufB, nullptr, N);
  // mu/logstd share aggregation; fused reparametrization
  agg16<<<aggGrid, 256, 0, stream>>>(bufB, bufA, rowptr, csr_src, dis, N);
  gemm_mfma<1><<<gemmGrid, 256, lds2, stream>>>(bufA, Wt + 2*16384, bmu, Wt + 3*16384, bls, eps, dis, bufB, nullptr, N);
  // layer 5
  agg16<<<aggGrid, 256, 0, stream>>>(bufB, bufA, rowptr, csr_src, dis, N);
  gemm_mfma<0><<<gemmGrid, 256, lds1, stream>>>(bufA, Wt + 4*16384, b5, nullptr, nullptr, nullptr, dis, bufB, nullptr, N);
  // layer 6 -> f32 d_out
  agg16<<<aggGrid, 256, 0, stream>>>(bufB, bufA, rowptr, csr_src, dis, N);
  gemm_mfma<2><<<gemmGrid, 256, lds1, stream>>>(bufA, Wt + 5*16384, b6, nullptr, nullptr, nullptr, dis, nullptr, out, N);
}

// Round 5
// 396.553 us; speedup vs baseline: 2.1499x; 1.1524x over previous
//
#include <hip/hip_runtime.h>
#include <hip/hip_bf16.h>
#include <cstdint>
#include <cstddef>

#define D 128
#define NWG 200        // workgroups for edge binning passes

typedef _Float16 f16;
typedef f16 f16x2 __attribute__((ext_vector_type(2)));
typedef f16 f16x4 __attribute__((ext_vector_type(4)));
typedef f16 f16x8 __attribute__((ext_vector_type(8)));
typedef float f32x4 __attribute__((ext_vector_type(4)));

static inline size_t align256(size_t x){ return (x + 255) & ~(size_t)255; }

// ---------------------------------------------------------------------------
// int64 vs int32 edge_index detection (odd dwords of int64 data are all 0)
__global__ void detect_kernel(const int* __restrict__ ei, long long n32, int* __restrict__ flag){
  __shared__ int s;
  if (threadIdx.x == 0) s = 0;
  __syncthreads();
  int nz = 0;
  for (long long i = 2LL*threadIdx.x + 1; i < 4096 && i < n32; i += 512)
    nz |= (ei[i] != 0);
  if (nz) s = 1;
  __syncthreads();
  if (threadIdx.x == 0) *flag = (s ? 0 : 1);   // 1 => int64
}

__device__ __forceinline__ void load_edge(const void* ei, int E, int is64, int e, int& s, int& d){
  if (is64) {
    const long long* p = (const long long*)ei;
    s = (int)p[e]; d = (int)p[(size_t)E + e];
  } else {
    const int* p = (const int*)ei;
    s = p[e]; d = p[(size_t)E + e];
  }
}

// ---------------------------------------------------------------------------
// Pass A: per-(bucket, wg) histogram via LDS counters. No global atomics.
__global__ __launch_bounds__(256) void passA_hist(
    const void* __restrict__ ei, int E, const int* __restrict__ flag,
    int* __restrict__ glob_hist, int NB){
  __shared__ int cnt[256];
  int t = threadIdx.x, wg = blockIdx.x;
  cnt[t] = 0;
  __syncthreads();
  int is64 = *flag;
  int chunk = (E + NWG - 1) / NWG;
  int lo = wg * chunk, hi = min(lo + chunk, E);
  for (int e = lo + t; e < hi; e += 256){
    int s, d;
    load_edge(ei, E, is64, e, s, d);
    atomicAdd(&cnt[d >> 8], 1);
  }
  __syncthreads();
  for (int b = t; b < NB; b += 256)
    glob_hist[b * NWG + wg] = cnt[b];
}

// ---------- generic exclusive scan (3 kernels) ----------
__global__ void scan_partial(const int* __restrict__ src, int* __restrict__ dst,
                             int* __restrict__ blockSums, int L){
  __shared__ int sd[256];
  int t = threadIdx.x;
  int base = blockIdx.x * 1024 + t * 4;
  int v[4]; int s = 0;
  #pragma unroll
  for (int j = 0; j < 4; ++j){ v[j] = (base + j < L) ? src[base + j] : 0; s += v[j]; }
  sd[t] = s; __syncthreads();
  for (int off = 1; off < 256; off <<= 1){
    int x = (t >= off) ? sd[t - off] : 0;
    __syncthreads();
    sd[t] += x;
    __syncthreads();
  }
  int run = sd[t] - s;
  #pragma unroll
  for (int j = 0; j < 4; ++j){
    if (base + j < L) dst[base + j] = run;
    run += v[j];
  }
  if (t == 255) blockSums[blockIdx.x] = sd[255];
}

__global__ void scan_blocksums(int* __restrict__ blockSums, int nblk,
                               int* __restrict__ dst, int L, int total){
  __shared__ int sd[256];
  int t = threadIdx.x;
  int v = (t < nblk) ? blockSums[t] : 0;
  sd[t] = v; __syncthreads();
  for (int off = 1; off < 256; off <<= 1){
    int x = (t >= off) ? sd[t - off] : 0;
    __syncthreads();
    sd[t] += x;
    __syncthreads();
  }
  if (t < nblk) blockSums[t] = sd[t] - v;
  if (t == 0) dst[L] = total;
}

__global__ void scan_add(int* __restrict__ dst, const int* __restrict__ blockSums, int L){
  int i = blockIdx.x * blockDim.x + threadIdx.x;
  if (i >= L) return;
  dst[i] += blockSums[i >> 10];
}

// ---------------------------------------------------------------------------
// Pass B: scatter packed edges (src | dstLow<<16) into bucket-grouped array.
__global__ __launch_bounds__(256) void passB_scatter(
    const void* __restrict__ ei, int E, const int* __restrict__ flag,
    const int* __restrict__ bucketOff, int NB, unsigned* __restrict__ packed){
  __shared__ int cur[256];
  int t = threadIdx.x, wg = blockIdx.x;
  for (int b = t; b < NB; b += 256)
    cur[b] = bucketOff[b * NWG + wg];
  __syncthreads();
  int is64 = *flag;
  int chunk = (E + NWG - 1) / NWG;
  int lo = wg * chunk, hi = min(lo + chunk, E);
  for (int e = lo + t; e < hi; e += 256){
    int s, d;
    load_edge(ei, E, is64, e, s, d);
    int pos = atomicAdd(&cur[d >> 8], 1);
    packed[pos] = (unsigned)s | ((unsigned)(d & 255) << 16);
  }
}

// ---------------------------------------------------------------------------
// Pass C: one wg per bucket. Local counts -> scan -> rowptr/dis -> csr_src.
__global__ __launch_bounds__(256) void passC_csr(
    const unsigned* __restrict__ packed, const int* __restrict__ bucketOff,
    int NB, int N, int E,
    int* __restrict__ rowptr, float* __restrict__ dis, int* __restrict__ csr_src){
  __shared__ int degl[256];
  __shared__ int sd[256];
  __shared__ int cur[256];
  int t = threadIdx.x, b = blockIdx.x;
  int begin = bucketOff[(size_t)b * NWG];
  int endb  = bucketOff[(size_t)(b + 1) * NWG];
  degl[t] = 0;
  __syncthreads();
  for (int i = begin + t; i < endb; i += 256)
    atomicAdd(&degl[(packed[i] >> 16) & 255], 1);
  __syncthreads();
  int dv = degl[t];
  sd[t] = dv; __syncthreads();
  for (int off = 1; off < 256; off <<= 1){
    int x = (t >= off) ? sd[t - off] : 0;
    __syncthreads();
    sd[t] += x;
    __syncthreads();
  }
  int localOff = sd[t] - dv;
  int v = b * 256 + t;
  if (v < N){
    rowptr[v] = begin + localOff;
    dis[v] = rsqrtf((float)(dv + 1));
  }
  if (b == NB - 1 && t == 0) rowptr[N] = E;
  cur[t] = begin + localOff;
  __syncthreads();
  for (int i = begin + t; i < endb; i += 256){
    unsigned p = packed[i];
    int pos = atomicAdd(&cur[(p >> 16) & 255], 1);
    csr_src[pos] = (int)(p & 0xFFFFu);
  }
}

// ---------------------------------------------------------------------------
// cast + pre-scale: out[v][c] = f16(in[v][c] * dis[v])
__global__ void cast_scale(const float* __restrict__ in, const float* __restrict__ dis,
                           f16* __restrict__ out, int n4){
  int i = blockIdx.x * blockDim.x + threadIdx.x;
  if (i >= n4) return;
  float dv = dis[i >> 5];
  float4 v = ((const float4*)in)[i];
  f16x4 o; o[0]=(f16)(v.x*dv); o[1]=(f16)(v.y*dv); o[2]=(f16)(v.z*dv); o[3]=(f16)(v.w*dv);
  ((f16x4*)out)[i] = o;
}

// transpose+cast 6 weight matrices: Wt[w][n][k] = W_w[k][n], fp16
__global__ void prep_w(const float* __restrict__ Wa, const float* __restrict__ Wb,
                       const float* __restrict__ Wc, const float* __restrict__ Wd,
                       const float* __restrict__ We, const float* __restrict__ Wf,
                       f16* __restrict__ Wt){
  int i = blockIdx.x * 256 + threadIdx.x;
  int w = i >> 14, rem = i & 16383;
  int n = rem >> 7, k = rem & 127;
  const float* Wp = (w==0)?Wa:(w==1)?Wb:(w==2)?Wc:(w==3)?Wd:(w==4)?We:Wf;
  Wt[i] = (f16)Wp[k*128 + n];
}

// ---------------------------------------------------------------------------
// unweighted fp16 aggregation over pre-scaled activations:
//   out[v] = f16( dis[v] * ( sum_{u->v} in[u] + in[v] ) )
// one wave per node; lane covers channels 2c,2c+1; 8 gathers in flight
__global__ __launch_bounds__(256) void agg16(
    const f16* __restrict__ in, f16* __restrict__ out,
    const int* __restrict__ rowptr, const int* __restrict__ csr_src,
    const float* __restrict__ dis, int N){
  int v = blockIdx.x * 4 + (threadIdx.x >> 6);
  if (v >= N) return;
  int c2 = (threadIdx.x & 63) * 2;
  float dv = dis[v];
  int beg = rowptr[v], end = rowptr[v + 1];
  f16x2 sv = *(const f16x2*)&in[(size_t)v * D + c2];
  float acc0 = (float)sv[0], acc1 = (float)sv[1];
  int e = beg;
  for (; e + 7 < end; e += 8){
    f16x2 h[8];
    #pragma unroll
    for (int j = 0; j < 8; ++j){
      int u = csr_src[e + j];
      h[j] = *(const f16x2*)&in[(size_t)u * D + c2];
    }
    #pragma unroll
    for (int j = 0; j < 8; ++j){ acc0 += (float)h[j][0]; acc1 += (float)h[j][1]; }
  }
  for (; e + 1 < end; e += 2){
    int u0 = csr_src[e], u1 = csr_src[e + 1];
    f16x2 h0 = *(const f16x2*)&in[(size_t)u0 * D + c2];
    f16x2 h1 = *(const f16x2*)&in[(size_t)u1 * D + c2];
    acc0 += (float)h0[0] + (float)h1[0];
    acc1 += (float)h0[1] + (float)h1[1];
  }
  if (e < end){
    int u = csr_src[e];
    f16x2 h = *(const f16x2*)&in[(size_t)u * D + c2];
    acc0 += (float)h[0]; acc1 += (float)h[1];
  }
  f16x2 o; o[0] = (f16)(acc0 * dv); o[1] = (f16)(acc1 * dv);
  *(f16x2*)&out[(size_t)v * D + c2] = o;
}

// ---------------------------------------------------------------------------
// MFMA GEMM (swapped operands): out = A[N,128](fp16) @ W[128,128] + epilogue.
//   EPI 0: fp16 out = relu(AW + b) * dis[r]
//   EPI 1: fp16 out = ((A Wmu + bmu) + eps * exp(A Wls + bls) * 0.1) * dis[r]
//   EPI 2: f32  out = relu(AW + b)            (final layer -> d_out)
// Block = 512 thr = 8 waves, 128 rows/block; W (Wt[n][k]) staged once in LDS
// with 16B-quad XOR swizzle. Per wave: 16 rows x 128 cols.
// mfma(X=Wt-slice, Y=A-rows): X row i -> out col n0+i; Y col j -> out row r0+j.
// D layout: lane holds OUT[r0+(l&15)][n0+(l>>4)*4+ii] -> f16x4 row-contiguous
// stores, float4 eps/bias loads.  [m89-verified fragment layouts]
template<int EPI>
__global__ __launch_bounds__(512) void gemm_mfma(
    const f16* __restrict__ A, const f16* __restrict__ Wt, const float* __restrict__ bias,
    const f16* __restrict__ Wt2, const float* __restrict__ bias2,
    const float* __restrict__ eps, const float* __restrict__ dis,
    f16* __restrict__ out16, float* __restrict__ outf, int N){

  extern __shared__ __align__(16) f16 Ws[];   // [128][128] (+ second matrix for EPI1)

  int t = threadIdx.x;
  int wave = t >> 6, lane = t & 63;
  int lrow = lane & 15, hi = lane >> 4;
  int r0 = blockIdx.x * 128 + wave * 16;
  bool active = (r0 < N);

  // ---- A fragments first (overlap staging latency); clamped row for tail
  f16x8 a[4];
  if (active){
    int rr = min(r0 + lrow, N - 1);
    const f16* arow = &A[(size_t)rr * D + hi * 8];
    #pragma unroll
    for (int s = 0; s < 4; ++s) a[s] = *(const f16x8*)&arow[s * 32];
  }

  // ---- stage W (quad-swizzled): 512 thr, 4 per row, 4 quads each
  {
    int r = t & 127, p = t >> 7;                 // p in 0..3
    const float4* src = (const float4*)&Wt[r * 128 + p * 32];
    f16* dstrow = &Ws[r * 128];
    #pragma unroll
    for (int i = 0; i < 4; ++i){
      int q = p * 4 + i;
      *(float4*)&dstrow[(q ^ (r & 7)) * 8] = src[i];
    }
    if (EPI == 1){
      const float4* src2 = (const float4*)&Wt2[r * 128 + p * 32];
      f16* dstrow2 = &Ws[16384 + r * 128];
      #pragma unroll
      for (int i = 0; i < 4; ++i){
        int q = p * 4 + i;
        *(float4*)&dstrow2[(q ^ (r & 7)) * 8] = src2[i];
      }
    }
  }
  __syncthreads();
  if (!active) return;

  f32x4 acc[8] = {};
  f32x4 acc2[8] = {};

  #pragma unroll
  for (int s = 0; s < 4; ++s){
    #pragma unroll
    for (int tt = 0; tt < 8; ++tt){
      int n = tt * 16 + lrow;
      int q = (s * 4 + hi) ^ (lrow & 7);
      f16x8 b = *(const f16x8*)&Ws[n * 128 + q * 8];
      acc[tt] = __builtin_amdgcn_mfma_f32_16x16x32_f16(b, a[s], acc[tt], 0, 0, 0);
      if (EPI == 1){
        f16x8 b2 = *(const f16x8*)&Ws[16384 + n * 128 + q * 8];
        acc2[tt] = __builtin_amdgcn_mfma_f32_16x16x32_f16(b2, a[s], acc2[tt], 0, 0, 0);
      }
    }
  }

  // ---- epilogue: lane owns row r = r0+lrow, cols n0 = tt*16 + hi*4 (+0..3)
  int r = r0 + lrow;
  if (r >= N) return;
  float dv = (EPI == 2) ? 1.f : dis[r];
  int cbase = hi * 4;
  #pragma unroll
  for (int tt = 0; tt < 8; ++tt){
    int n0 = tt * 16 + cbase;
    f32x4 bv = *(const f32x4*)&bias[n0];
    if (EPI == 0){
      f16x4 o;
      #pragma unroll
      for (int ii = 0; ii < 4; ++ii)
        o[ii] = (f16)(fmaxf(acc[tt][ii] + bv[ii], 0.f) * dv);
      *(f16x4*)&out16[(size_t)r * D + n0] = o;
    } else if (EPI == 1){
      f32x4 bv2 = *(const f32x4*)&bias2[n0];
      f32x4 e4  = *(const f32x4*)&eps[(size_t)r * D + n0];
      f16x4 o;
      #pragma unroll
      for (int ii = 0; ii < 4; ++ii){
        float mu = acc[tt][ii] + bv[ii];
        float ls = acc2[tt][ii] + bv2[ii];
        o[ii] = (f16)((mu + e4[ii] * __expf(ls) * 0.1f) * dv);
      }
      *(f16x4*)&out16[(size_t)r * D + n0] = o;
    } else {
      f32x4 o;
      #pragma unroll
      for (int ii = 0; ii < 4; ++ii)
        o[ii] = fmaxf(acc[tt][ii] + bv[ii], 0.f);
      *(f32x4*)&outf[(size_t)r * D + n0] = o;
    }
  }
}

// ---------------------------------------------------------------------------
extern "C" void kernel_launch(void* const* d_in, const int* in_sizes, int n_in,
                              void* d_out, int out_size, void* d_ws, size_t ws_size,
                              hipStream_t stream){
  const float* x   = (const float*)d_in[0];
  const void*  ei  = d_in[1];
  const float* eps = (const float*)d_in[2];
  const float* W1  = (const float*)d_in[3];  const float* b1  = (const float*)d_in[4];
  const float* W2  = (const float*)d_in[5];  const float* b2  = (const float*)d_in[6];
  const float* Wmu = (const float*)d_in[7];  const float* bmu = (const float*)d_in[8];
  const float* Wls = (const float*)d_in[9];  const float* bls = (const float*)d_in[10];
  const float* W5  = (const float*)d_in[11]; const float* b5  = (const float*)d_in[12];
  const float* W6  = (const float*)d_in[13]; const float* b6  = (const float*)d_in[14];

  const int N = in_sizes[0] / D;
  const int E = in_sizes[1] / 2;
  const int NB = (N + 255) >> 8;
  const int L  = NB * NWG;
  float* out = (float*)d_out;

  char* ws = (char*)d_ws;
  size_t off = 0;
  auto alloc = [&](size_t bytes){ char* p = ws + off; off += align256(bytes); return p; };
  int*      flag      = (int*)     alloc(256);
  int*      glob_hist = (int*)     alloc(((size_t)L + 1) * 4);
  int*      bucketOff = (int*)     alloc(((size_t)L + 1) * 4);
  int*      blockSums = (int*)     alloc(1024);
  int*      rowptr    = (int*)     alloc(((size_t)N + 1) * 4);
  float*    dis       = (float*)   alloc((size_t)N * 4);
  unsigned* packed    = (unsigned*)alloc((size_t)E * 4);
  int*      csr_src   = (int*)     alloc((size_t)E * 4);
  f16*      Wt        = (f16*)     alloc((size_t)6 * 128 * 128 * 2);
  f16*      bufA      = (f16*)     alloc((size_t)N * D * 2);
  f16*      bufB      = (f16*)     alloc((size_t)N * D * 2);
  (void)ws_size; (void)n_in; (void)out_size;

  detect_kernel<<<1, 256, 0, stream>>>((const int*)ei, (long long)2 * E, flag);

  // CSR build: LDS-staged counting sort by dst bucket (no global atomics)
  passA_hist<<<NWG, 256, 0, stream>>>(ei, E, flag, glob_hist, NB);
  int nblk = (L + 1023) / 1024;
  scan_partial<<<nblk, 256, 0, stream>>>(glob_hist, bucketOff, blockSums, L);
  scan_blocksums<<<1, 256, 0, stream>>>(blockSums, nblk, bucketOff, L, E);
  scan_add<<<(L + 255) / 256, 256, 0, stream>>>(bucketOff, blockSums, L);
  passB_scatter<<<NWG, 256, 0, stream>>>(ei, E, flag, bucketOff, NB, packed);
  passC_csr<<<NB, 256, 0, stream>>>(packed, bucketOff, NB, N, E, rowptr, dis, csr_src);

  cast_scale<<<(N * D / 4 + 255) / 256, 256, 0, stream>>>(x, dis, bufB, N * D / 4);
  prep_w<<<(6 * 16384) / 256, 256, 0, stream>>>(W1, W2, Wmu, Wls, W5, W6, Wt);

  int aggGrid = (N + 3) / 4;
  int gemmGrid = (N + 127) / 128;
  size_t lds1 = 128 * 128 * sizeof(f16);       // 32 KB
  size_t lds2 = 2 * 128 * 128 * sizeof(f16);   // 64 KB (EPI1)

  // layer 1
  agg16<<<aggGrid, 256, 0, stream>>>(bufB, bufA, rowptr, csr_src, dis, N);
  gemm_mfma<0><<<gemmGrid, 512, lds1, stream>>>(bufA, Wt + 0*16384, b1, nullptr, nullptr, nullptr, dis, bufB, nullptr, N);
  // layer 2
  agg16<<<aggGrid, 256, 0, stream>>>(bufB, bufA, rowptr, csr_src, dis, N);
  gemm_mfma<0><<<gemmGrid, 512, lds1, stream>>>(bufA, Wt + 1*16384, b2, nullptr, nullptr, nullptr, dis, bufB, nullptr, N);
  // mu/logstd share aggregation; fused reparametrization
  agg16<<<aggGrid, 256, 0, stream>>>(bufB, bufA, rowptr, csr_src, dis, N);
  gemm_mfma<1><<<gemmGrid, 512, lds2, stream>>>(bufA, Wt + 2*16384, bmu, Wt + 3*16384, bls, eps, dis, bufB, nullptr, N);
  // layer 5
  agg16<<<aggGrid, 256, 0, stream>>>(bufB, bufA, rowptr, csr_src, dis, N);
  gemm_mfma<0><<<gemmGrid, 512, lds1, stream>>>(bufA, Wt + 4*16384, b5, nullptr, nullptr, nullptr, dis, bufB, nullptr, N);
  // layer 6 -> f32 d_out
  agg16<<<aggGrid, 256, 0, stream>>>(bufB, bufA, rowptr, csr_src, dis, N);
  gemm_mfma<2><<<gemmGrid, 512, lds1, stream>>>(bufA, Wt + 5*16384, b6, nullptr, nullptr, nullptr, dis, nullptr, out, N);
}